// Round 4
// baseline (459.586 us; speedup 1.0000x reference)
//
#include <hip/hip_runtime.h>

#define B_  4
#define H_  1080
#define W_  1920
#define HW_ (H_*W_)

#define TS   32          // tile size
#define HALO 3
#define P    38          // TS + 2*HALO
#define PS   40          // padded LDS row stride (f32 ref gray)
#define PSd  40          // padded LDS row stride (f64 tgt gray)
#define ES   37          // edge plane stride (region is 36 wide)

// ws layout (32-bit slots): [0]=max_diff bits, [1]=max_cdiff bits, [2..5]=per-batch diff sums (float)

__global__ __launch_bounds__(256) void k_reduce(const float* __restrict__ ref,
                                                const float* __restrict__ tgt,
                                                unsigned int* __restrict__ ws) {
    const int b = blockIdx.y;
    const float4* r0 = (const float4*)(ref + (size_t)b * 3 * HW_);
    const float4* t0 = (const float4*)(tgt + (size_t)b * 3 * HW_);
    const int NV = HW_ / 4;
    float maxd = 0.f, maxc = 0.f, sumd = 0.f;
    for (int i = blockIdx.x * blockDim.x + threadIdx.x; i < NV; i += gridDim.x * blockDim.x) {
        float4 ra = r0[i], rb = r0[i + NV], rc = r0[i + 2*NV];
        float4 ta = t0[i], tb = t0[i + NV], tc = t0[i + 2*NV];
        #define DO_LANE(f) { \
            float d0 = ra.f - ta.f, d1 = rb.f - tb.f, d2 = rc.f - tc.f; \
            float dd = sqrtf(d0*d0 + d1*d1 + d2*d2); \
            float cd = (fabsf(d0) + fabsf(d1) + fabsf(d2)) * (1.f/3.f); \
            maxd = fmaxf(maxd, dd); maxc = fmaxf(maxc, cd); sumd += dd; }
        DO_LANE(x) DO_LANE(y) DO_LANE(z) DO_LANE(w)
        #undef DO_LANE
    }
    for (int off = 32; off > 0; off >>= 1) {
        maxd = fmaxf(maxd, __shfl_xor(maxd, off));
        maxc = fmaxf(maxc, __shfl_xor(maxc, off));
        sumd += __shfl_xor(sumd, off);
    }
    __shared__ float red[12];
    const int tid = threadIdx.x, wid = tid >> 6;
    if ((tid & 63) == 0) { red[wid] = maxd; red[4+wid] = maxc; red[8+wid] = sumd; }
    __syncthreads();
    if (tid == 0) {
        maxd = fmaxf(fmaxf(red[0], red[1]), fmaxf(red[2], red[3]));
        maxc = fmaxf(fmaxf(red[4], red[5]), fmaxf(red[6], red[7]));
        sumd = red[8] + red[9] + red[10] + red[11];
        atomicMax(&ws[0], __float_as_uint(maxd));
        atomicMax(&ws[1], __float_as_uint(maxc));
        atomicAdd((float*)&ws[2 + b], sumd);
    }
}

__global__ void k_score(const unsigned int* __restrict__ ws, float* __restrict__ out) {
    int b = threadIdx.x;
    if (b < B_) {
        float den = __uint_as_float(ws[0]) + 1e-12f;
        float s = ((const float*)ws)[2 + b];
        float score = 1.f - (s / den) * (1.f / (float)HW_);
        out[b] = fminf(fmaxf(score, 0.f), 1.f);
    }
}

__global__ __launch_bounds__(256) void k_main(const float* __restrict__ ref,
                                              const float* __restrict__ tgt,
                                              const unsigned int* __restrict__ ws,
                                              float* __restrict__ out) {
    __shared__ float  sGr[P*PS];     // ref gray f32 (ssim only — continuous)
    __shared__ double sGt[P*PSd];    // tgt gray f64 (Sobel thresholds need f64)
    __shared__ float  sTmp[P*TS];    // separable scratch (hsum / hmax)
    __shared__ float  sEdge[36*ES];  // edges at tile+halo2
    __shared__ float  sAnom[TS*TS];  // anomaly for ringing

    const int tx0 = blockIdx.x * TS, ty0 = blockIdx.y * TS, b = blockIdx.z;
    const int tid = threadIdx.x;
    const float den_d = __uint_as_float(ws[0]) + 1e-12f;
    const float den_c = __uint_as_float(ws[1]) + 1e-12f;
    const float* rb = ref + (size_t)b * 3 * HW_;
    const float* tb = tgt + (size_t)b * 3 * HW_;
    float* outb = out + 4 + (size_t)b * 5 * HW_;

    // ---- load + gray + (center) anomaly/color ----
    for (int i = tid; i < P*P; i += 256) {
        int py = i / P, px = i - py * P;
        int gy = ty0 + py - HALO, gx = tx0 + px - HALO;
        float r0=0.f,r1=0.f,r2=0.f,t0=0.f,t1=0.f,t2=0.f;
        bool inb = (gy >= 0) & (gy < H_) & (gx >= 0) & (gx < W_);
        int o = gy * W_ + gx;
        if (inb) {
            r0 = rb[o]; r1 = rb[o + HW_]; r2 = rb[o + 2*HW_];
            t0 = tb[o]; t1 = tb[o + HW_]; t2 = tb[o + 2*HW_];
        }
        // f64 gray (matches NumPy promotion: f32 * f64-weights -> f64)
        double grd = ((double)r0*0.299 + (double)r1*0.587) + (double)r2*0.114;
        double gtd = ((double)t0*0.299 + (double)t1*0.587) + (double)t2*0.114;
        sGr[py*PS  + px] = (float)grd;
        sGt[py*PSd + px] = gtd;
        int cy = py - HALO, cx = px - HALO;
        if (cy >= 0 && cy < TS && cx >= 0 && cx < TS && inb) {
            float d0 = r0-t0, d1 = r1-t1, d2 = r2-t2;
            float dd = sqrtf(d0*d0 + d1*d1 + d2*d2);
            float cd = (fabsf(d0) + fabsf(d1) + fabsf(d2)) * (1.f/3.f);
            float an = dd / den_d;
            outb[o] = an;
            outb[HW_ + o] = cd / den_c;
            sAnom[cy*TS + cx] = an;
        }
    }
    __syncthreads();

    // ---- 7x7 box, separable: ref ----
    for (int i = tid; i < P*TS; i += 256) {
        int ry = i >> 5, rx = i & 31;
        const float* g = &sGr[ry*PS + rx];
        sTmp[i] = g[0]+g[1]+g[2]+g[3]+g[4]+g[5]+g[6];
    }
    __syncthreads();
    float mu_r[4];
    #pragma unroll
    for (int k = 0; k < 4; k++) {
        int i = tid + k*256;
        int cy = i >> 5, cx = i & 31;
        const float* h = &sTmp[cy*TS + cx];
        mu_r[k] = (h[0]+h[32]+h[64]+h[96]+h[128]+h[160]+h[192]) * (1.f/49.f);
    }
    __syncthreads();
    // ---- 7x7 box, separable: tgt + ssim write ----
    for (int i = tid; i < P*TS; i += 256) {
        int ry = i >> 5, rx = i & 31;
        const double* g = &sGt[ry*PSd + rx];
        sTmp[i] = (float)g[0]+(float)g[1]+(float)g[2]+(float)g[3]+(float)g[4]+(float)g[5]+(float)g[6];
    }
    __syncthreads();
    #pragma unroll
    for (int k = 0; k < 4; k++) {
        int i = tid + k*256;
        int cy = i >> 5, cx = i & 31;
        const float* h = &sTmp[cy*TS + cx];
        float mt = (h[0]+h[32]+h[64]+h[96]+h[128]+h[160]+h[192]) * (1.f/49.f);
        float mr = mu_r[k];
        int gy = ty0 + cy, gx = tx0 + cx;
        if (gy < H_)
            outb[2*HW_ + gy*W_ + gx] = (2.f*mr*mt + 1e-4f) / (mr*mr + mt*mt + 1e-4f);
    }

    // ---- Sobel (f64) -> edges (halo 2) + blocking write at center ----
    // edges exist only inside the image; -inf dilation padding == 0 here.
    for (int i = tid; i < 36*36; i += 256) {
        int ey = i / 36, ex = i - ey*36;
        int py = ey + 1, px = ex + 1;           // padded coords
        int gy = ty0 + ey - 2, gx = tx0 + ex - 2;
        bool inb = (gy >= 0) & (gy < H_) & (gx >= 0) & (gx < W_);
        const double* g = &sGt[py*PSd + px];
        double a00 = g[-PSd-1], a01 = g[-PSd], a02 = g[-PSd+1];
        double a10 = g[-1],                    a12 = g[1];
        double a20 = g[PSd-1],  a21 = g[PSd],  a22 = g[PSd+1];
        double gxv = fabs((a02 + 2.0*a12 + a22) - (a00 + 2.0*a10 + a20));
        double gyv = fabs((a20 + 2.0*a21 + a22) - (a00 + 2.0*a01 + a02));
        double s2 = gxv*gxv + gyv*gyv;
        sEdge[ey*ES + ex] = (inb && s2 > (0.15*0.15)) ? 1.f : 0.f;
        int cy = ey - 2, cx = ex - 2;
        if (cy >= 0 && cy < TS && cx >= 0 && cx < TS && inb) {
            double bv = ((gx & 7) == 0) ? gxv : 0.0;
            if ((gy & 7) == 0) bv = fmax(bv, gyv);
            outb[3*HW_ + gy*W_ + gx] = (bv > 0.05) ? 1.f : 0.f;
        }
    }
    __syncthreads();

    // ---- 5x5 dilation, separable: hmax ----
    for (int i = tid; i < 36*TS; i += 256) {
        int ry = i >> 5, cx = i & 31;
        const float* e = &sEdge[ry*ES + cx];    // window ex-2..ex+2 == cx..cx+4
        sTmp[i] = fmaxf(fmaxf(fmaxf(e[0], e[1]), fmaxf(e[2], e[3])), e[4]);
    }
    __syncthreads();
    #pragma unroll
    for (int k = 0; k < 4; k++) {
        int i = tid + k*256;
        int cy = i >> 5, cx = i & 31;
        const float* h = &sTmp[cy*TS + cx];
        float dil = fmaxf(fmaxf(fmaxf(h[0], h[32]), fmaxf(h[64], h[96])), h[128]);
        float ec  = sEdge[(cy+2)*ES + cx + 2];
        float ring = fmaxf(dil - ec, 0.f) * sAnom[cy*TS + cx];
        int gy = ty0 + cy, gx = tx0 + cx;
        if (gy < H_) outb[4*HW_ + gy*W_ + gx] = ring;
    }
}

extern "C" void kernel_launch(void* const* d_in, const int* in_sizes, int n_in,
                              void* d_out, int out_size, void* d_ws, size_t ws_size,
                              hipStream_t stream) {
    const float* ref = (const float*)d_in[0];
    const float* tgt = (const float*)d_in[1];
    float* out = (float*)d_out;
    unsigned int* ws = (unsigned int*)d_ws;

    hipMemsetAsync(d_ws, 0, 6 * sizeof(unsigned int), stream);
    k_reduce<<<dim3(512, B_), 256, 0, stream>>>(ref, tgt, ws);
    k_score<<<1, 64, 0, stream>>>(ws, out);
    k_main<<<dim3(W_/TS, (H_ + TS - 1)/TS, B_), 256, 0, stream>>>(ref, tgt, ws, out);
}